// Round 3
// baseline (43.316 us; speedup 1.0000x reference)
//
#include <hip/hip_runtime.h>

// Separable factorization of the 3x3 window: w = outer(v,v), v = [A_W, B_W, A_W]
#define A_W 0.30780133f
#define B_W 0.38439735f

#define IMG_W 512
#define CROP_LO 5
#define CROP_HI 507          // exclusive; rows/cols 5..506 kept (502 each)
#define STRIP 16
#define NSTRIPS 32           // ceil(502/16)
#define BLOCK_THREADS 128    // 128 threads x 4 cols = 512 cols (full row width)

struct Raw {                 // raw inputs for one row, 4 owned cols + halos
    float4 x, y;
    float xl, xr, yl, yr;
};

struct H {                   // horizontal weighted sums for 4 cols
    float s1[4], s2[4], s11[4], s22[4], s12[4];
};

__device__ __forceinline__ Raw load_row(const float* __restrict__ Xr,
                                        const float* __restrict__ Yr,
                                        int c0, int cl, int cr) {
    Raw R;
    R.x  = *(const float4*)(Xr + c0);
    R.y  = *(const float4*)(Yr + c0);
    R.xl = Xr[cl]; R.xr = Xr[cr];
    R.yl = Yr[cl]; R.yr = Yr[cr];
    return R;
}

__device__ __forceinline__ void hcompute(const Raw& R, H& o) {
    float Xa[6] = {R.xl, R.x.x, R.x.y, R.x.z, R.x.w, R.xr};
    float Ya[6] = {R.yl, R.y.x, R.y.y, R.y.z, R.y.w, R.yr};
#pragma unroll
    for (int k = 0; k < 4; ++k) {
        float xl = Xa[k], xc = Xa[k + 1], xr = Xa[k + 2];
        float yl = Ya[k], yc = Ya[k + 1], yr = Ya[k + 2];
        o.s1[k]  = A_W * (xl + xr)           + B_W * xc;
        o.s2[k]  = A_W * (yl + yr)           + B_W * yc;
        o.s11[k] = A_W * (xl * xl + xr * xr) + B_W * (xc * xc);
        o.s22[k] = A_W * (yl * yl + yr * yr) + B_W * (yc * yc);
        o.s12[k] = A_W * (xl * yl + xr * yr) + B_W * (xc * yc);
    }
}

__global__ __launch_bounds__(BLOCK_THREADS, 4) void ssim_loss_main(
    const float* __restrict__ X, const float* __restrict__ Y,
    float* __restrict__ partials) {
    const int t  = threadIdx.x;
    const int c0 = 4 * t;
    const int cl = max(c0 - 1, 0);
    const int cr = min(c0 + 4, IMG_W - 1);
    const int b  = blockIdx.y;
    const int i0 = CROP_LO + blockIdx.x * STRIP;   // 5..501

    const float* Xb = X + (size_t)b * IMG_W * IMG_W;
    const float* Yb = Y + (size_t)b * IMG_W * IMG_W;

    float vmask[4];
#pragma unroll
    for (int k = 0; k < 4; ++k)
        vmask[k] = (c0 + k >= CROP_LO && c0 + k < CROP_HI) ? 1.0f : 0.0f;

    // Prologue: rows i0-1, i0, i0+1
    Raw rA = load_row(Xb + (size_t)(i0 - 1) * IMG_W, Yb + (size_t)(i0 - 1) * IMG_W, c0, cl, cr);
    Raw rB = load_row(Xb + (size_t)i0 * IMG_W,       Yb + (size_t)i0 * IMG_W,       c0, cl, cr);
    Raw rN = load_row(Xb + (size_t)(i0 + 1) * IMG_W, Yb + (size_t)(i0 + 1) * IMG_W, c0, cl, cr);
    H P, C;
    hcompute(rA, P);
    hcompute(rB, C);

    float acc = 0.0f;
#pragma unroll 4
    for (int r = 0; r < STRIP; ++r) {
        H N;
        hcompute(rN, N);
        // Prefetch row i0+r+2 (clamped; masked rows just recompute row 507).
        const int rnext = min(i0 + r + 2, CROP_HI);
        rN = load_row(Xb + (size_t)rnext * IMG_W, Yb + (size_t)rnext * IMG_W, c0, cl, cr);

        float racc = 0.0f;
#pragma unroll
        for (int k = 0; k < 4; ++k) {
            float s1  = A_W * (P.s1[k]  + N.s1[k])  + B_W * C.s1[k];
            float s2  = A_W * (P.s2[k]  + N.s2[k])  + B_W * C.s2[k];
            float s11 = A_W * (P.s11[k] + N.s11[k]) + B_W * C.s11[k];
            float s22 = A_W * (P.s22[k] + N.s22[k]) + B_W * C.s22[k];
            float s12 = A_W * (P.s12[k] + N.s12[k]) + B_W * C.s12[k];
            float v1 = s11 - s1 * s1;
            float v2 = s22 - s2 * s2;
            float cv = s12 - s1 * s2;
            racc += vmask[k] * (v1 * v2 - 2.0f * cv);
        }
        acc += (i0 + r < CROP_HI) ? racc : 0.0f;   // row mask (tail strip)
        P = C; C = N;
    }

    // Block reduction: 2 waves.
    for (int off = 32; off > 0; off >>= 1) acc += __shfl_down(acc, off, 64);
    __shared__ float wsum[BLOCK_THREADS / 64];
    if ((t & 63) == 0) wsum[t >> 6] = acc;
    __syncthreads();
    if (t == 0)
        partials[blockIdx.x + NSTRIPS * blockIdx.y] = wsum[0] + wsum[1];
}

__global__ __launch_bounds__(256) void ssim_loss_finalize(
    const float* __restrict__ partials, int n, float* __restrict__ out) {
    const int tid = threadIdx.x;
    float s = 0.0f;
    for (int i = tid; i < n; i += 256) s += partials[i];
    for (int off = 32; off > 0; off >>= 1) s += __shfl_down(s, off, 64);
    __shared__ float wsum[4];
    if ((tid & 63) == 0) wsum[tid >> 6] = s;
    __syncthreads();
    if (tid == 0) {
        float total = wsum[0] + wsum[1] + wsum[2] + wsum[3];
        out[0] = total * (1.0f / 252004.0f);   // mean over 502*502, summed over batch
    }
}

extern "C" void kernel_launch(void* const* d_in, const int* in_sizes, int n_in,
                              void* d_out, int out_size, void* d_ws, size_t ws_size,
                              hipStream_t stream) {
    const float* X = (const float*)d_in[0];
    const float* Y = (const float*)d_in[1];
    float* out = (float*)d_out;
    float* partials = (float*)d_ws;   // NSTRIPS*64 = 2048 floats

    dim3 grid(NSTRIPS, 64);
    ssim_loss_main<<<grid, BLOCK_THREADS, 0, stream>>>(X, Y, partials);
    ssim_loss_finalize<<<1, 256, 0, stream>>>(partials, NSTRIPS * 64, out);
}

// Round 5
// 29.870 us; speedup vs baseline: 1.4502x; 1.4502x over previous
//
#include <hip/hip_runtime.h>

// Separable 3x3 window: w = outer(v,v), v = [A_W, B_W, A_W]
#define A_W 0.30780133f
#define B_W 0.38439735f

#define IMG_W 512
#define CROP_LO 5
#define CROP_HI 507          // exclusive; rows/cols 5..506 kept (502 each)
#define STRIP 32
#define NSTRIPS 16
#define NCOLBLK 2
#define BLOCK_THREADS 256

struct Raw6 { float xl, xc, xr, yl, yc, yr; };
struct H5   { float s1, s2, s11, s22, s12; };

__device__ __forceinline__ Raw6 ld_row(const float* __restrict__ Xb,
                                       const float* __restrict__ Yb,
                                       int row, int c) {
    const float* Xr = Xb + (size_t)row * IMG_W;
    const float* Yr = Yb + (size_t)row * IMG_W;
    Raw6 r;
    r.xl = Xr[c - 1]; r.xc = Xr[c]; r.xr = Xr[c + 1];
    r.yl = Yr[c - 1]; r.yc = Yr[c]; r.yr = Yr[c + 1];
    return r;
}

__device__ __forceinline__ H5 hsum(const Raw6& r) {
    H5 h;
    h.s1  = A_W * (r.xl + r.xr)               + B_W * r.xc;
    h.s2  = A_W * (r.yl + r.yr)               + B_W * r.yc;
    h.s11 = A_W * (r.xl * r.xl + r.xr * r.xr) + B_W * (r.xc * r.xc);
    h.s22 = A_W * (r.yl * r.yl + r.yr * r.yr) + B_W * (r.yc * r.yc);
    h.s12 = A_W * (r.xl * r.yl + r.xr * r.yr) + B_W * (r.xc * r.yc);
    return h;
}

__global__ __launch_bounds__(BLOCK_THREADS) void ssim_loss_main(
    const float* __restrict__ X, const float* __restrict__ Y,
    float* __restrict__ partials) {
    const int t  = threadIdx.x;
    const int c  = CROP_LO + blockIdx.x * BLOCK_THREADS + t;  // 5..516
    const int cc = min(c, IMG_W - 2);                         // safe load col
    const float vm = (c < CROP_HI) ? 1.0f : 0.0f;             // col mask
    const int b  = blockIdx.z;
    const int i0 = CROP_LO + blockIdx.y * STRIP;              // 5..485

    const float* Xb = X + (size_t)b * IMG_W * IMG_W;
    const float* Yb = Y + (size_t)b * IMG_W * IMG_W;

    // Pipeline prologue: h-state for rows i0-1, i0; raw rows i0+1, i0+2 in flight.
    Raw6 rA = ld_row(Xb, Yb, i0 - 1, cc);
    Raw6 rB = ld_row(Xb, Yb, i0,     cc);
    Raw6 rC = ld_row(Xb, Yb, i0 + 1, cc);
    Raw6 rD = ld_row(Xb, Yb, i0 + 2, cc);
    H5 P = hsum(rA);
    H5 C = hsum(rB);

    float acc = 0.0f;
#pragma unroll
    for (int r = 0; r < STRIP; ++r) {
        // Issue loads for row i0+r+3 (2 iterations ahead of use).
        Raw6 rNew = ld_row(Xb, Yb, min(i0 + r + 3, IMG_W - 1), cc);

        H5 N = hsum(rC);

        float s1  = A_W * (P.s1  + N.s1)  + B_W * C.s1;
        float s2  = A_W * (P.s2  + N.s2)  + B_W * C.s2;
        float s11 = A_W * (P.s11 + N.s11) + B_W * C.s11;
        float s22 = A_W * (P.s22 + N.s22) + B_W * C.s22;
        float s12 = A_W * (P.s12 + N.s12) + B_W * C.s12;

        float v1 = s11 - s1 * s1;      // sigma1_sq
        float v2 = s22 - s2 * s2;      // sigma2_sq
        float cv = s12 - s1 * s2;      // sigma12
        float term = v1 * v2 - 2.0f * cv;

        acc += (i0 + r < CROP_HI) ? vm * term : 0.0f;

        P = C; C = N; rC = rD; rD = rNew;
    }

    // Block reduction: 4 waves.
    for (int off = 32; off > 0; off >>= 1) acc += __shfl_down(acc, off, 64);
    __shared__ float wsum[BLOCK_THREADS / 64];
    if ((t & 63) == 0) wsum[t >> 6] = acc;
    __syncthreads();
    if (t == 0)
        partials[blockIdx.x + NCOLBLK * (blockIdx.y + NSTRIPS * blockIdx.z)] =
            wsum[0] + wsum[1] + wsum[2] + wsum[3];
}

__global__ __launch_bounds__(256) void ssim_loss_finalize(
    const float* __restrict__ partials, int n, float* __restrict__ out) {
    const int tid = threadIdx.x;
    float s = 0.0f;
    for (int i = tid; i < n; i += 256) s += partials[i];
    for (int off = 32; off > 0; off >>= 1) s += __shfl_down(s, off, 64);
    __shared__ float wsum[4];
    if ((tid & 63) == 0) wsum[tid >> 6] = s;
    __syncthreads();
    if (tid == 0) {
        float total = wsum[0] + wsum[1] + wsum[2] + wsum[3];
        out[0] = total * (1.0f / 252004.0f);   // mean over 502*502, summed over batch
    }
}

extern "C" void kernel_launch(void* const* d_in, const int* in_sizes, int n_in,
                              void* d_out, int out_size, void* d_ws, size_t ws_size,
                              hipStream_t stream) {
    const float* X = (const float*)d_in[0];
    const float* Y = (const float*)d_in[1];
    float* out = (float*)d_out;
    float* partials = (float*)d_ws;   // NCOLBLK*NSTRIPS*64 = 2048 floats

    dim3 grid(NCOLBLK, NSTRIPS, 64);
    ssim_loss_main<<<grid, BLOCK_THREADS, 0, stream>>>(X, Y, partials);
    ssim_loss_finalize<<<1, 256, 0, stream>>>(partials, NCOLBLK * NSTRIPS * 64, out);
}